// Round 4
// baseline (336.569 us; speedup 1.0000x reference)
//
#include <hip/hip_runtime.h>
#include <math.h>

#define O_CH 32
#define I_CH 3
#define IH 512
#define IW 512
#define OH 510
#define OW 510
#define N_IMG 16
#define WSTRIDE 32       // weight row stride in d_ws

typedef float v2f __attribute__((ext_vector_type(2)));

__global__ __launch_bounds__(256) void gabor_weights_kernel(
    const float* __restrict__ freq, const float* __restrict__ theta,
    const float* __restrict__ psi, const float* __restrict__ sigma,
    float* __restrict__ wp) {
  int idx = blockIdx.x * 256 + threadIdx.x;
  if (idx >= O_CH * I_CH * 9) return;
  int o = idx / 27;
  int rem = idx % 27;          // rem = c*9 + kh*3 + kw
  int kh = (rem / 3) % 3;
  int kw = rem % 3;
  // linspace(-ceil(3/2)+1, ceil(3/2), 3) = {-1, 0.5, 2}
  float x = (kw == 0) ? -1.0f : (kw == 1 ? 0.5f : 2.0f);
  float y = (kh == 0) ? -1.0f : (kh == 1 ? 0.5f : 2.0f);
  int pi = o * I_CH + rem / 9; // (O,I) parameter index
  float th = theta[pi], f = freq[pi], p = psi[pi], s = sigma[pi];
  float ct = cosf(th), st = sinf(th);
  float rotx = x * ct + y * st;
  float roty = -x * st + y * ct;
  float se = s + 0.001f;
  float g = expf(-0.5f * (rotx * rotx + roty * roty) / (se * se));
  g *= cosf(f * rotx + p);
  g /= (2.0f * 3.14f * s * s);   // reference uses PI = 3.14 exactly
  wp[o * WSTRIDE + rem] = g;
}

// One wave == 2 output rows x 256 cols (lane owns 4 consecutive px on each of
// 2 rows) for all 32 o. Stores are 2x back-to-back float2 per row per o
// (16B/lane, 50% line density per instr, merged in L2), nontemporal so the
// 533MB output stream doesn't evict input halos from L2. Blocks are
// XCD-chunk-swizzled so row-adjacent blocks share a per-XCD L2.
__global__ __launch_bounds__(256) void gabor_conv_kernel(
    const float* __restrict__ in, const float* __restrict__ wgp,
    float* __restrict__ out) {
  // Weights per (o,c) padded to 12 floats (float4-aligned rows)
  __shared__ float sW[O_CH][I_CH * 12];

  const int tid = threadIdx.x;
  for (int i = tid; i < O_CH * I_CH * 12; i += 256) {
    int o = i / 36;
    int t = i % 36;
    int c = t / 12;
    int j = t % 12;
    sW[o][t] = (j < 9) ? wgp[o * WSTRIDE + c * 9 + j] : 0.0f;
  }
  __syncthreads();

  const int wave = tid >> 6;   // 0..3
  const int lane = tid & 63;

  // chunked XCD swizzle (bijective: nwg=2048, nwg%8==0, q=256)
  const int bid = blockIdx.y * gridDim.x + blockIdx.x;
  const int q = (gridDim.x * gridDim.y) >> 3;
  const int nid = (bid & 7) * q + (bid >> 3);
  const int n  = nid >> 7;          // image 0..15
  const int bx = nid & 127;         // ypair-pair index 0..127
  const int yp = bx * 2 + (wave >> 1);   // row-pair 0..255 (255 invalid)
  const int xh = wave & 1;
  if (yp >= 255) return;            // uniform per-wave tail (after barrier)

  const int y0 = yp * 2;            // rows y0, y0+1 (max 509 -> loads <=511)
  const int x0 = (xh << 8) + lane * 4;   // 0..508

  const float* inN = in + (size_t)n * I_CH * IH * IW;

  // Input window: 3 ch x 4 rows x 6 cols in 72 VGPRs
  float r[I_CH][4][6];
#pragma unroll
  for (int c = 0; c < I_CH; ++c) {
#pragma unroll
    for (int rw = 0; rw < 4; ++rw) {
      const float* rowp = inN + (c * IH + y0 + rw) * IW;
      float4 A = *(const float4*)&rowp[x0];            // 16B aligned
      int xc = x0 + 4; if (xc > IW - 2) xc = IW - 2;   // lane63/xh1 clamp
      float2 B = *(const float2*)&rowp[xc];
      r[c][rw][0] = A.x; r[c][rw][1] = A.y; r[c][rw][2] = A.z; r[c][rw][3] = A.w;
      r[c][rw][4] = B.x; r[c][rw][5] = B.y;
    }
  }

  const bool full = (x0 + 4 <= OW);   // false only for lane 63, xh==1
  float* outN = out + (size_t)n * O_CH * OH * OW;
  const float4* sW4base = (const float4*)&sW[0][0];

#pragma unroll 2
  for (int o = 0; o < O_CH; ++o) {
    float a00 = 0.f, a01 = 0.f, a02 = 0.f, a03 = 0.f;   // row y0
    float a10 = 0.f, a11 = 0.f, a12 = 0.f, a13 = 0.f;   // row y0+1
#pragma unroll
    for (int c = 0; c < I_CH; ++c) {
      const float4* w4 = sW4base + o * 9 + c * 3;   // broadcast ds_read_b128
      float4 w0 = w4[0], w1 = w4[1], w2 = w4[2];
      float wq[9];
      wq[0] = w0.x; wq[1] = w0.y; wq[2] = w0.z; wq[3] = w0.w;
      wq[4] = w1.x; wq[5] = w1.y; wq[6] = w1.z; wq[7] = w1.w;
      wq[8] = w2.x;
#pragma unroll
      for (int kh = 0; kh < 3; ++kh) {
#pragma unroll
        for (int kw = 0; kw < 3; ++kw) {
          float w = wq[kh * 3 + kw];
          a00 = fmaf(r[c][kh + 0][kw + 0], w, a00);
          a01 = fmaf(r[c][kh + 0][kw + 1], w, a01);
          a02 = fmaf(r[c][kh + 0][kw + 2], w, a02);
          a03 = fmaf(r[c][kh + 0][kw + 3], w, a03);
          a10 = fmaf(r[c][kh + 1][kw + 0], w, a10);
          a11 = fmaf(r[c][kh + 1][kw + 1], w, a11);
          a12 = fmaf(r[c][kh + 1][kw + 2], w, a12);
          a13 = fmaf(r[c][kh + 1][kw + 3], w, a13);
        }
      }
    }
    size_t ob = ((size_t)o * OH + y0) * OW + x0;   // even -> 8B aligned
    v2f s00 = {a00, a01}, s01 = {a02, a03};
    v2f s10 = {a10, a11}, s11 = {a12, a13};
    __builtin_nontemporal_store(s00, (v2f*)(outN + ob));
    __builtin_nontemporal_store(s10, (v2f*)(outN + ob + OW));
    if (full) {
      __builtin_nontemporal_store(s01, (v2f*)(outN + ob + 2));
      __builtin_nontemporal_store(s11, (v2f*)(outN + ob + OW + 2));
    }
  }
}

extern "C" void kernel_launch(void* const* d_in, const int* in_sizes, int n_in,
                              void* d_out, int out_size, void* d_ws, size_t ws_size,
                              hipStream_t stream) {
  const float* img   = (const float*)d_in[0];
  const float* freq  = (const float*)d_in[1];
  const float* theta = (const float*)d_in[2];
  const float* psi   = (const float*)d_in[3];
  const float* sigma = (const float*)d_in[4];
  float* outp = (float*)d_out;
  float* wgp = (float*)d_ws;  // 32x32 floats of scratch (Gabor weights)

  gabor_weights_kernel<<<dim3(4), dim3(256), 0, stream>>>(freq, theta, psi, sigma, wgp);

  dim3 grid(128, N_IMG);   // 2048 blocks; block = 2 row-pairs x 2 x-halves
  gabor_conv_kernel<<<grid, dim3(256), 0, stream>>>(img, wgp, outp);
}

// Round 5
// 149.222 us; speedup vs baseline: 2.2555x; 2.2555x over previous
//
#include <hip/hip_runtime.h>
#include <math.h>

#define O_CH 32
#define I_CH 3
#define IH 512
#define IW 512
#define OH 510
#define OW 510
#define N_IMG 16
#define WSTRIDE 32       // weight row stride in d_ws

typedef float v2f __attribute__((ext_vector_type(2)));
typedef float v4f __attribute__((ext_vector_type(4)));

__global__ __launch_bounds__(256) void gabor_weights_kernel(
    const float* __restrict__ freq, const float* __restrict__ theta,
    const float* __restrict__ psi, const float* __restrict__ sigma,
    float* __restrict__ wp) {
  int idx = blockIdx.x * 256 + threadIdx.x;
  if (idx >= O_CH * I_CH * 9) return;
  int o = idx / 27;
  int rem = idx % 27;          // rem = c*9 + kh*3 + kw
  int kh = (rem / 3) % 3;
  int kw = rem % 3;
  // linspace(-ceil(3/2)+1, ceil(3/2), 3) = {-1, 0.5, 2}
  float x = (kw == 0) ? -1.0f : (kw == 1 ? 0.5f : 2.0f);
  float y = (kh == 0) ? -1.0f : (kh == 1 ? 0.5f : 2.0f);
  int pi = o * I_CH + rem / 9; // (O,I) parameter index
  float th = theta[pi], f = freq[pi], p = psi[pi], s = sigma[pi];
  float ct = cosf(th), st = sinf(th);
  float rotx = x * ct + y * st;
  float roty = -x * st + y * ct;
  float se = s + 0.001f;
  float g = expf(-0.5f * (rotx * rotx + roty * roty) / (se * se));
  g *= cosf(f * rotx + p);
  g /= (2.0f * 3.14f * s * s);   // reference uses PI = 3.14 exactly
  wp[o * WSTRIDE + rem] = g;
}

// One wave == 2 output rows x 256 cols (lane owns 4 consecutive px on each of
// 2 rows) for all 32 o. Regular (L2-merged) stores: R3's nontemporal stores
// doubled WRITE_SIZE (1.04 GB vs 533 MB ideal) via unmerged partial lines.
// Even output rows are 16B-aligned -> one dwordx4 store; odd rows 2x float2.
// Blocks are XCD-chunk-swizzled so row-adjacent blocks share a per-XCD L2
// (measured: FETCH_SIZE 24.6 MB, near-perfect input reuse).
__global__ __launch_bounds__(256) void gabor_conv_kernel(
    const float* __restrict__ in, const float* __restrict__ wgp,
    float* __restrict__ out) {
  // Weights per (o,c) padded to 12 floats (float4-aligned rows)
  __shared__ float sW[O_CH][I_CH * 12];

  const int tid = threadIdx.x;
  for (int i = tid; i < O_CH * I_CH * 12; i += 256) {
    int o = i / 36;
    int t = i % 36;
    int c = t / 12;
    int j = t % 12;
    sW[o][t] = (j < 9) ? wgp[o * WSTRIDE + c * 9 + j] : 0.0f;
  }
  __syncthreads();

  const int wave = tid >> 6;   // 0..3
  const int lane = tid & 63;

  // chunked XCD swizzle (bijective: nwg=2048, nwg%8==0, q=256)
  const int bid = blockIdx.y * gridDim.x + blockIdx.x;
  const int q = (gridDim.x * gridDim.y) >> 3;
  const int nid = (bid & 7) * q + (bid >> 3);
  const int n  = nid >> 7;          // image 0..15
  const int bx = nid & 127;         // ypair-pair index 0..127
  const int yp = bx * 2 + (wave >> 1);   // row-pair 0..255 (255 invalid)
  const int xh = wave & 1;
  if (yp >= 255) return;            // uniform per-wave tail (after barrier)

  const int y0 = yp * 2;            // rows y0 (even), y0+1; max 509
  const int x0 = (xh << 8) + lane * 4;   // 0..508

  const float* inN = in + (size_t)n * I_CH * IH * IW;

  // Input window: 3 ch x 4 rows x 6 cols in 72 VGPRs
  float r[I_CH][4][6];
#pragma unroll
  for (int c = 0; c < I_CH; ++c) {
#pragma unroll
    for (int rw = 0; rw < 4; ++rw) {
      const float* rowp = inN + (c * IH + y0 + rw) * IW;
      float4 A = *(const float4*)&rowp[x0];            // 16B aligned
      int xc = x0 + 4; if (xc > IW - 2) xc = IW - 2;   // lane63/xh1 clamp
      float2 B = *(const float2*)&rowp[xc];
      r[c][rw][0] = A.x; r[c][rw][1] = A.y; r[c][rw][2] = A.z; r[c][rw][3] = A.w;
      r[c][rw][4] = B.x; r[c][rw][5] = B.y;
    }
  }

  const bool full = (x0 + 4 <= OW);   // false only for lane 63, xh==1
  float* outN = out + (size_t)n * O_CH * OH * OW;
  const float4* sW4base = (const float4*)&sW[0][0];

#pragma unroll 2
  for (int o = 0; o < O_CH; ++o) {
    float a00 = 0.f, a01 = 0.f, a02 = 0.f, a03 = 0.f;   // row y0
    float a10 = 0.f, a11 = 0.f, a12 = 0.f, a13 = 0.f;   // row y0+1
#pragma unroll
    for (int c = 0; c < I_CH; ++c) {
      const float4* w4 = sW4base + o * 9 + c * 3;   // broadcast ds_read_b128
      float4 w0 = w4[0], w1 = w4[1], w2 = w4[2];
      float wq[9];
      wq[0] = w0.x; wq[1] = w0.y; wq[2] = w0.z; wq[3] = w0.w;
      wq[4] = w1.x; wq[5] = w1.y; wq[6] = w1.z; wq[7] = w1.w;
      wq[8] = w2.x;
#pragma unroll
      for (int kh = 0; kh < 3; ++kh) {
#pragma unroll
        for (int kw = 0; kw < 3; ++kw) {
          float w = wq[kh * 3 + kw];
          a00 = fmaf(r[c][kh + 0][kw + 0], w, a00);
          a01 = fmaf(r[c][kh + 0][kw + 1], w, a01);
          a02 = fmaf(r[c][kh + 0][kw + 2], w, a02);
          a03 = fmaf(r[c][kh + 0][kw + 3], w, a03);
          a10 = fmaf(r[c][kh + 1][kw + 0], w, a10);
          a11 = fmaf(r[c][kh + 1][kw + 1], w, a11);
          a12 = fmaf(r[c][kh + 1][kw + 2], w, a12);
          a13 = fmaf(r[c][kh + 1][kw + 3], w, a13);
        }
      }
    }
    size_t ob = ((size_t)o * OH + y0) * OW + x0;   // even row: ob % 4 == 0
    if (full) {
      v4f s0 = {a00, a01, a02, a03};
      *(v4f*)(outN + ob) = s0;                       // dwordx4, 16B aligned
      *(v2f*)(outN + ob + OW) = (v2f){a10, a11};     // odd row: 8B aligned
      *(v2f*)(outN + ob + OW + 2) = (v2f){a12, a13};
    } else {
      *(v2f*)(outN + ob) = (v2f){a00, a01};
      *(v2f*)(outN + ob + OW) = (v2f){a10, a11};
    }
  }
}

extern "C" void kernel_launch(void* const* d_in, const int* in_sizes, int n_in,
                              void* d_out, int out_size, void* d_ws, size_t ws_size,
                              hipStream_t stream) {
  const float* img   = (const float*)d_in[0];
  const float* freq  = (const float*)d_in[1];
  const float* theta = (const float*)d_in[2];
  const float* psi   = (const float*)d_in[3];
  const float* sigma = (const float*)d_in[4];
  float* outp = (float*)d_out;
  float* wgp = (float*)d_ws;  // 32x32 floats of scratch (Gabor weights)

  gabor_weights_kernel<<<dim3(4), dim3(256), 0, stream>>>(freq, theta, psi, sigma, wgp);

  dim3 grid(128, N_IMG);   // 2048 blocks; block = 2 row-pairs x 2 x-halves
  gabor_conv_kernel<<<grid, dim3(256), 0, stream>>>(img, wgp, outp);
}